// Round 7
// baseline (175.436 us; speedup 1.0000x reference)
//
#include <hip/hip_runtime.h>
#include <hip/hip_bf16.h>
#include <stdint.h>

// Problem constants
#define NB   64          // batch*windows
#define NTOK 196         // tokens per window
#define NH   32          // heads
#define HD   4           // head dim
#define CE   128         // embed
#define NM   38416       // 196*196

typedef __bf16 bf16x8 __attribute__((ext_vector_type(8)));
typedef short  bf16x4s __attribute__((ext_vector_type(4)));
typedef float  f32x4  __attribute__((ext_vector_type(4)));

#define QSCALE 0.7213475204444817f   /* 0.5 * log2(e) */
#define LOG2E  1.4426950408889634f

__device__ __forceinline__ float u2f(unsigned short u) {
    union { unsigned int i; float f; } z;
    z.i = ((unsigned int)u) << 16;
    return z.f;
}
__device__ __forceinline__ unsigned short f2u(float f) {
    union { float f; unsigned int i; } z; z.f = f;
    unsigned int x = z.i;
    return (unsigned short)((x + 0x7fffu + ((x >> 16) & 1u)) >> 16); // RNE
}

// ---------------------------------------------------------------------------
// Kernel 1: QKV GEMM (MFMA, C^T = W·X^T) + bias_build merged as grid.y==6.
// Qb/Kb packed bf16 [b,h][n][br*4+d] (Q pre-scaled), V bf16 [b][2H][n][d].
// bias: [h][qt 13][kt 7][lane 64][8 shorts] bf16*log2e, C-frag order of
// S^T tiles (row=key=quad*4+reg, col=query=tc); -inf in padding.
// ---------------------------------------------------------------------------
extern "C" __global__ __launch_bounds__(256) void qkv_bias(
    const float* __restrict__ x1,
    const float* __restrict__ x2,
    const float* __restrict__ qkvw,
    const int* __restrict__ rel_idx, const float* __restrict__ rpb,
    unsigned short* __restrict__ Qb, unsigned short* __restrict__ Kb,
    unsigned short* __restrict__ V, unsigned short* __restrict__ biasM)
{
    __shared__ alignas(16) unsigned short AT[64][136];   // X rows (tokens)
    __shared__ alignas(16) unsigned short BT[64][136];   // W rows (j)
    const int tid = threadIdx.x;

    if (blockIdx.y == 6) {
        // ---- bias path: 416 blocks = 13 qt x 32 h ----
        const int bx = blockIdx.x;
        const int qt = bx % 13, h = bx / 13;
        const int lane = tid & 63, wv = tid >> 6;
        const int quad = lane >> 4, tc = lane & 15;
        for (int nt = wv; nt < 14; nt += 4) {
            union { uint2 v; unsigned short s[4]; } e;
#pragma unroll
            for (int r = 0; r < 4; ++r) {
                int q   = qt * 16 + tc;              // query = col
                int key = nt * 16 + quad * 4 + r;    // key   = row
                unsigned short u = 0xFF80;           // -inf bf16
                if (q < 196 && key < 196) {
                    int idx = rel_idx[q * 196 + key];
                    u = f2u(rpb[idx * 32 + h] * LOG2E);
                }
                e.s[r] = u;
            }
            unsigned int off = (((h * 13 + qt) * 7 + (nt >> 1)) * 64 + lane) * 8
                               + (nt & 1) * 4;
            *(uint2*)(biasM + off) = e.v;
        }
        return;
    }
    if (blockIdx.x >= 392) return;

    const int r0 = blockIdx.x * 64;     // token rows (both branches stacked)
    const int j0 = blockIdx.y * 64;     // cols of 384

    for (int idx = tid; idx < 2048; idx += 256) {
        int row = idx >> 5, k0 = (idx & 31) << 2;
        int r = r0 + row;
        const float* xp = (r >= 12544) ? x2 : x1;
        int rem = r - ((r >= 12544) ? 12544 : 0);
        float4 v = *(const float4*)&xp[rem * 128 + k0];
        ushort4 u; u.x = f2u(v.x); u.y = f2u(v.y); u.z = f2u(v.z); u.w = f2u(v.w);
        *(ushort4*)&AT[row][k0] = u;
    }
    for (int idx = tid; idx < 2048; idx += 256) {
        int row = idx >> 5, k0 = (idx & 31) << 2;
        float4 v = *(const float4*)&qkvw[(j0 + row) * 128 + k0];
        ushort4 u; u.x = f2u(v.x); u.y = f2u(v.y); u.z = f2u(v.z); u.w = f2u(v.w);
        *(ushort4*)&BT[row][k0] = u;
    }
    __syncthreads();

    const int lane = tid & 63, w = tid >> 6;
    const int wj = (w >> 1) * 32;    // j offset (M dim)
    const int wt = (w & 1) * 32;     // token offset (N dim)
    const int quad = lane >> 4, tc = lane & 15;

    f32x4 acc[2][2] = {};
#pragma unroll
    for (int ks = 0; ks < 4; ++ks) {
        int k0 = ks * 32 + quad * 8;
        bf16x8 a0 = *(const bf16x8*)&BT[wj + tc][k0];
        bf16x8 a1 = *(const bf16x8*)&BT[wj + 16 + tc][k0];
        bf16x8 b0 = *(const bf16x8*)&AT[wt + tc][k0];
        bf16x8 b1 = *(const bf16x8*)&AT[wt + 16 + tc][k0];
        acc[0][0] = __builtin_amdgcn_mfma_f32_16x16x32_bf16(a0, b0, acc[0][0], 0, 0, 0);
        acc[0][1] = __builtin_amdgcn_mfma_f32_16x16x32_bf16(a0, b1, acc[0][1], 0, 0, 0);
        acc[1][0] = __builtin_amdgcn_mfma_f32_16x16x32_bf16(a1, b0, acc[1][0], 0, 0, 0);
        acc[1][1] = __builtin_amdgcn_mfma_f32_16x16x32_bf16(a1, b1, acc[1][1], 0, 0, 0);
    }

    const int sel = j0 >> 7;   // 0=q 1=k 2=v, uniform per block
#pragma unroll
    for (int mi = 0; mi < 2; ++mi) {
        int jbase = (j0 + wj + mi * 16 + quad * 4) & 127;
        int hh = jbase >> 2;
#pragma unroll
        for (int ni = 0; ni < 2; ++ni) {
            int tok = r0 + wt + ni * 16 + tc;
            int branch = (tok >= 12544) ? 1 : 0;
            int rem = tok - branch * 12544;
            int bb = rem / 196;
            int nn = rem - bb * 196;
            union { uint2 v; unsigned short s[4]; } pk2;
            if (sel == 0) {
#pragma unroll
                for (int r = 0; r < 4; ++r) pk2.s[r] = f2u(acc[mi][ni][r] * QSCALE);
                *(uint2*)&Qb[((bb * 32 + hh) * 196 + nn) * 8 + branch * 4] = pk2.v;
            } else if (sel == 1) {
#pragma unroll
                for (int r = 0; r < 4; ++r) pk2.s[r] = f2u(acc[mi][ni][r]);
                *(uint2*)&Kb[((bb * 32 + hh) * 196 + nn) * 8 + branch * 4] = pk2.v;
            } else {
#pragma unroll
                for (int r = 0; r < 4; ++r) pk2.s[r] = f2u(acc[mi][ni][r]);
                *(uint2*)&V[(bb * 64 + branch * 32 + hh) * 784 + nn * 4] = pk2.v;
            }
        }
    }
}

// ---------------------------------------------------------------------------
// Kernel 2: MFMA attention with the conv-gated InstanceNorm fusion folded into
// the staging phase. Block = (b,h): computes fused V channel h (dot over 64
// channels + instance-norm + sigmoid(relu)) -> VT bf16 (with ones row), then
// S^T = K·Q^T (bias as C-init), exp2, perm-pack, PV via 16x16x16 (B-frag ==
// C-frag layout). Dual O accumulators halve the PV dependency chain; per-qt
// bias tiles prefetched to registers.
// ---------------------------------------------------------------------------
__device__ __forceinline__ float block_sum(float v, float* red, int tid) {
#pragma unroll
    for (int off = 32; off > 0; off >>= 1) v += __shfl_down(v, off);
    __syncthreads();
    if ((tid & 63) == 0) red[tid >> 6] = v;
    __syncthreads();
    return red[0] + red[1] + red[2] + red[3];
}

__device__ __forceinline__ float act_sig_relu(float x) {
    return x > 0.f ? __fdividef(1.f, 1.f + __expf(-x)) : 0.5f;
}

extern "C" __global__ __launch_bounds__(256) void attn_kernel(
    const unsigned short* __restrict__ Qb, const unsigned short* __restrict__ Kb,
    const unsigned short* __restrict__ V, const float* __restrict__ fuse_w,
    const float* __restrict__ fuse_b, const unsigned short* __restrict__ biasM,
    unsigned short* __restrict__ Ob)
{
    const int bh = blockIdx.x;
    const int b = bh >> 5, h = bh & 31;
    __shared__ alignas(16) unsigned short Qs[208][8];
    __shared__ alignas(16) unsigned short Ks[224][8];
    __shared__ alignas(16) unsigned short VT[16][232];
    __shared__ float fws[64];
    __shared__ float red[4];
    const int tid = threadIdx.x;

    // ---- stage Q/K (zero-padded) ----
    const unsigned short* Qrow = Qb + bh * 196 * 8;
    const unsigned short* Krow = Kb + bh * 196 * 8;
    if (tid < 208) {
        uint4 z = {0, 0, 0, 0};
        uint4 v = (tid < 196) ? *(const uint4*)(Qrow + tid * 8) : z;
        *(uint4*)&Qs[tid][0] = v;
    }
    if (tid < 224) {
        uint4 z = {0, 0, 0, 0};
        uint4 v = (tid < 196) ? *(const uint4*)(Krow + tid * 8) : z;
        *(uint4*)&Ks[tid][0] = v;
    }
    {
        unsigned int* vtw = (unsigned int*)&VT[0][0];
        for (int i = tid; i < (16 * 232) / 2; i += 256) vtw[i] = 0u;
    }
    if (tid < 64) fws[tid] = fuse_w[h * 64 + tid];
    __syncthreads();

    // ---- fused value channel h: a[nd] = sum_c fw[h,c] * V[b,c,nd] ----
    const unsigned short* Vb = V + b * 64 * 784;
    float a0 = 0.f, a1 = 0.f, a2 = 0.f, t0 = 0.f;
    const bool tail = tid < 16;
    for (int c = 0; c < 64; ++c) {
        float w0 = fws[c];
        const unsigned short* Vc = Vb + c * 784;
        a0 = fmaf(w0, u2f(Vc[tid]),       a0);
        a1 = fmaf(w0, u2f(Vc[tid + 256]), a1);
        a2 = fmaf(w0, u2f(Vc[tid + 512]), a2);
        if (tail) t0 = fmaf(w0, u2f(Vc[tid + 768]), t0);
    }
    float fb0 = fuse_b[h];
    a0 += fb0; a1 += fb0; a2 += fb0; t0 += fb0;

    float s_  = a0 + a1 + a2 + (tail ? t0 : 0.f);
    float q_  = a0*a0 + a1*a1 + a2*a2 + (tail ? t0*t0 : 0.f);
    float S0 = block_sum(s_, red, tid);
    float Q0 = block_sum(q_, red, tid);
    const float inv784 = 1.0f / 784.0f;
    float mu = S0 * inv784;
    float rstd = rsqrtf(Q0 * inv784 - mu * mu + 1e-5f);

    // write fused channel into VT[d][n] (bf16), plus ones row VT[4][n]
    {
        float vals[4] = { act_sig_relu((a0 - mu) * rstd),
                          act_sig_relu((a1 - mu) * rstd),
                          act_sig_relu((a2 - mu) * rstd),
                          act_sig_relu((t0 - mu) * rstd) };
#pragma unroll
        for (int k = 0; k < 3; ++k) {
            int nd = tid + 256 * k;
            VT[nd & 3][nd >> 2] = f2u(vals[k]);
            if ((nd & 3) == 0) VT[4][nd >> 2] = 0x3F80;
        }
        if (tail) {
            int nd = tid + 768;
            VT[nd & 3][nd >> 2] = f2u(vals[3]);
            if ((nd & 3) == 0) VT[4][nd >> 2] = 0x3F80;
        }
    }
    __syncthreads();

    const int lane = tid & 63, wv = tid >> 6;
    const int quad = lane >> 4, tc = lane & 15;

    // Hoist V'^T 16x16x16 A-frags (qt-invariant): A[m=tc][k=quad*4+j], tile t
    bf16x4s vfr16[14];
#pragma unroll
    for (int t = 0; t < 14; ++t)
        vfr16[t] = *(const bf16x4s*)&VT[tc][t * 16 + quad * 4];

    const unsigned short* bias_h = biasM + (unsigned)(h * 13) * 3584;

    for (int qt = wv; qt < 13; qt += 4) {
        bf16x8 bq = {};
        if (quad == 0) bq = *(const bf16x8*)&Qs[qt * 16 + tc][0];
        const unsigned short* bias_q = bias_h + qt * 3584;
        // prefetch all 7 bias tiles for this qt
        uint4 bw[7];
#pragma unroll
        for (int kt = 0; kt < 7; ++kt)
            bw[kt] = *(const uint4*)(bias_q + kt * 512 + lane * 8);
        f32x4 O0 = {}, O1 = {};
#pragma unroll
        for (int kt = 0; kt < 7; ++kt) {
            f32x4 s0, s1;
            {
                union { unsigned int u; float f; } c;
                c.u = bw[kt].x << 16;          s0[0] = c.f;
                c.u = bw[kt].x & 0xffff0000u;  s0[1] = c.f;
                c.u = bw[kt].y << 16;          s0[2] = c.f;
                c.u = bw[kt].y & 0xffff0000u;  s0[3] = c.f;
                c.u = bw[kt].z << 16;          s1[0] = c.f;
                c.u = bw[kt].z & 0xffff0000u;  s1[1] = c.f;
                c.u = bw[kt].w << 16;          s1[2] = c.f;
                c.u = bw[kt].w & 0xffff0000u;  s1[3] = c.f;
            }
            bf16x8 ka0 = *(const bf16x8*)&Ks[(kt * 2 + 0) * 16 + tc][0];
            bf16x8 ka1 = *(const bf16x8*)&Ks[(kt * 2 + 1) * 16 + tc][0];
            s0 = __builtin_amdgcn_mfma_f32_16x16x32_bf16(ka0, bq, s0, 0, 0, 0);
            s1 = __builtin_amdgcn_mfma_f32_16x16x32_bf16(ka1, bq, s1, 0, 0, 0);
            float e0 = __builtin_amdgcn_exp2f(s0[0]);
            float e1 = __builtin_amdgcn_exp2f(s0[1]);
            float e2 = __builtin_amdgcn_exp2f(s0[2]);
            float e3 = __builtin_amdgcn_exp2f(s0[3]);
            float g0 = __builtin_amdgcn_exp2f(s1[0]);
            float g1 = __builtin_amdgcn_exp2f(s1[1]);
            float g2 = __builtin_amdgcn_exp2f(s1[2]);
            float g3 = __builtin_amdgcn_exp2f(s1[3]);
            union { int d[2]; bf16x4s v; } pf0, pf1;
            pf0.d[0] = (int)__builtin_amdgcn_perm(__float_as_uint(e1), __float_as_uint(e0), 0x07060302u);
            pf0.d[1] = (int)__builtin_amdgcn_perm(__float_as_uint(e3), __float_as_uint(e2), 0x07060302u);
            pf1.d[0] = (int)__builtin_amdgcn_perm(__float_as_uint(g1), __float_as_uint(g0), 0x07060302u);
            pf1.d[1] = (int)__builtin_amdgcn_perm(__float_as_uint(g3), __float_as_uint(g2), 0x07060302u);
            O0 = __builtin_amdgcn_mfma_f32_16x16x16bf16_1k(vfr16[kt * 2 + 0], pf0.v, O0, 0, 0, 0);
            O1 = __builtin_amdgcn_mfma_f32_16x16x16bf16_1k(vfr16[kt * 2 + 1], pf1.v, O1, 0, 0, 0);
        }
        f32x4 Oacc;
        Oacc[0] = O0[0] + O1[0];
        Oacc[1] = O0[1] + O1[1];
        Oacc[2] = O0[2] + O1[2];
        Oacc[3] = O0[3] + O1[3];
        // O^T C-frag: rows d=quad*4+reg, col=query=tc. Rowsum = row 4.
        float rs = __shfl(Oacc[0], 16 + tc);
        int q = qt * 16 + tc;
        if (quad == 0 && q < 196) {
            float inv = __builtin_amdgcn_rcpf(rs);
            union { uint2 v; unsigned short s[4]; } pk2;
            pk2.s[0] = f2u(Oacc[0] * inv);
            pk2.s[1] = f2u(Oacc[1] * inv);
            pk2.s[2] = f2u(Oacc[2] * inv);
            pk2.s[3] = f2u(Oacc[3] * inv);
            *(uint2*)&Ob[(b * 196 + q) * 128 + h * 4] = pk2.v;
        }
    }
}

// ---------------------------------------------------------------------------
// Kernel 3: output projection via MFMA bf16. out = Ob @ projW^T + b (fp32 out)
// ---------------------------------------------------------------------------
extern "C" __global__ __launch_bounds__(256) void proj_kernel(
    const unsigned short* __restrict__ Ob, const float* __restrict__ projw,
    const float* __restrict__ projb, float* __restrict__ out)
{
    __shared__ alignas(16) unsigned short AT[64][136];
    __shared__ alignas(16) unsigned short BT[64][136];
    const int tid = threadIdx.x;
    const int r0 = blockIdx.x * 64;
    const int j0 = blockIdx.y * 64;

    for (int idx = tid; idx < 1024; idx += 256) {
        int row = idx >> 4, k0 = (idx & 15) << 3;
        *(uint4*)&AT[row][k0] = *(const uint4*)&Ob[(r0 + row) * 128 + k0];
    }
    for (int idx = tid; idx < 2048; idx += 256) {
        int row = idx >> 5, k0 = (idx & 31) << 2;
        float4 v = *(const float4*)&projw[(j0 + row) * 128 + k0];
        ushort4 u; u.x = f2u(v.x); u.y = f2u(v.y); u.z = f2u(v.z); u.w = f2u(v.w);
        *(ushort4*)&BT[row][k0] = u;
    }
    __syncthreads();

    const int lane = tid & 63, w = tid >> 6;
    const int wm = (w >> 1) * 32, wn = (w & 1) * 32;
    const int quad = lane >> 4, tcol = lane & 15;

    f32x4 acc[2][2] = {};
#pragma unroll
    for (int ks = 0; ks < 4; ++ks) {
        int k0 = ks * 32 + quad * 8;
        bf16x8 a0 = *(const bf16x8*)&AT[wm + tcol][k0];
        bf16x8 a1 = *(const bf16x8*)&AT[wm + 16 + tcol][k0];
        bf16x8 b0 = *(const bf16x8*)&BT[wn + tcol][k0];
        bf16x8 b1 = *(const bf16x8*)&BT[wn + 16 + tcol][k0];
        acc[0][0] = __builtin_amdgcn_mfma_f32_16x16x32_bf16(a0, b0, acc[0][0], 0, 0, 0);
        acc[0][1] = __builtin_amdgcn_mfma_f32_16x16x32_bf16(a0, b1, acc[0][1], 0, 0, 0);
        acc[1][0] = __builtin_amdgcn_mfma_f32_16x16x32_bf16(a1, b0, acc[1][0], 0, 0, 0);
        acc[1][1] = __builtin_amdgcn_mfma_f32_16x16x32_bf16(a1, b1, acc[1][1], 0, 0, 0);
    }

#pragma unroll
    for (int mi = 0; mi < 2; ++mi) {
#pragma unroll
        for (int ni = 0; ni < 2; ++ni) {
            int j = j0 + wn + ni * 16 + tcol;
            float pb = projb[j];
#pragma unroll
            for (int reg = 0; reg < 4; ++reg) {
                int r = r0 + wm + mi * 16 + quad * 4 + reg;
                out[r * 128 + j] = acc[mi][ni][reg] + pb;
            }
        }
    }
}

// ---------------------------------------------------------------------------
extern "C" void kernel_launch(void* const* d_in, const int* in_sizes, int n_in,
                              void* d_out, int out_size, void* d_ws, size_t ws_size,
                              hipStream_t stream)
{
    const float* x1    = (const float*)d_in[0];
    const float* x2    = (const float*)d_in[1];
    const float* qkvw  = (const float*)d_in[2];
    const float* projw = (const float*)d_in[3];
    const float* projb = (const float*)d_in[4];
    const float* rpb   = (const float*)d_in[5];
    const float* fw    = (const float*)d_in[6];
    const float* fb    = (const float*)d_in[7];
    const int*   rel   = (const int*)d_in[8];
    float* out = (float*)d_out;

    char* w = (char*)d_ws;
    unsigned short* Qb  = (unsigned short*)(w);              //  6,422,528 B
    unsigned short* Kb  = (unsigned short*)(w + 6422528);    //  6,422,528 B
    unsigned short* V   = (unsigned short*)(w + 12845056);   //  6,422,528 B
    unsigned short* bM  = (unsigned short*)(w + 19267584);   //  2,981,888 B
    unsigned short* Ob  = (unsigned short*)(w + 22249472);   //  3,211,264 B

    qkv_bias  <<<dim3(416, 7), dim3(256), 0, stream>>>(x1, x2, qkvw, rel, rpb,
                                                       Qb, Kb, V, bM);
    attn_kernel<<<dim3(2048),   dim3(256), 0, stream>>>(Qb, Kb, V, fw, fb, bM, Ob);
    proj_kernel<<<dim3(196, 2), dim3(256), 0, stream>>>(Ob, projw, projb, out);
}

// Round 8
// 155.076 us; speedup vs baseline: 1.1313x; 1.1313x over previous
//
#include <hip/hip_runtime.h>
#include <hip/hip_bf16.h>
#include <stdint.h>

// Problem constants
#define NB   64          // batch*windows
#define NTOK 196         // tokens per window
#define NH   32          // heads
#define HD   4           // head dim
#define CE   128         // embed
#define NM   38416       // 196*196

typedef __bf16 bf16x8 __attribute__((ext_vector_type(8)));
typedef short  bf16x4s __attribute__((ext_vector_type(4)));
typedef float  f32x4  __attribute__((ext_vector_type(4)));

#define QSCALE 0.7213475204444817f   /* 0.5 * log2(e) */
#define LOG2E  1.4426950408889634f

__device__ __forceinline__ float u2f(unsigned short u) {
    union { unsigned int i; float f; } z;
    z.i = ((unsigned int)u) << 16;
    return z.f;
}
__device__ __forceinline__ unsigned short f2u(float f) {
    union { float f; unsigned int i; } z; z.f = f;
    unsigned int x = z.i;
    return (unsigned short)((x + 0x7fffu + ((x >> 16) & 1u)) >> 16); // RNE
}

// ---------------------------------------------------------------------------
// Kernel 1: QKV GEMM (MFMA, C^T = W·X^T) + bias_build merged as grid.y==6.
// Qb/Kb packed bf16 [b,h][n][br*4+d] (Q pre-scaled), V bf16 [b][2H][n][d].
// bias: [h][qt 13][kt 7][lane 64][8 shorts] bf16*log2e, C-frag order of
// S^T tiles (row=key=quad*4+reg, col=query=tc); -inf in padding.
// ---------------------------------------------------------------------------
extern "C" __global__ __launch_bounds__(256) void qkv_bias(
    const float* __restrict__ x1,
    const float* __restrict__ x2,
    const float* __restrict__ qkvw,
    const int* __restrict__ rel_idx, const float* __restrict__ rpb,
    unsigned short* __restrict__ Qb, unsigned short* __restrict__ Kb,
    unsigned short* __restrict__ V, unsigned short* __restrict__ biasM)
{
    __shared__ alignas(16) unsigned short AT[64][136];   // X rows (tokens)
    __shared__ alignas(16) unsigned short BT[64][136];   // W rows (j)
    const int tid = threadIdx.x;

    if (blockIdx.y == 6) {
        // ---- bias path: 416 blocks = 13 qt x 32 h ----
        const int bx = blockIdx.x;
        const int qt = bx % 13, h = bx / 13;
        const int lane = tid & 63, wv = tid >> 6;
        const int quad = lane >> 4, tc = lane & 15;
        for (int nt = wv; nt < 14; nt += 4) {
            union { uint2 v; unsigned short s[4]; } e;
#pragma unroll
            for (int r = 0; r < 4; ++r) {
                int q   = qt * 16 + tc;              // query = col
                int key = nt * 16 + quad * 4 + r;    // key   = row
                unsigned short u = 0xFF80;           // -inf bf16
                if (q < 196 && key < 196) {
                    int idx = rel_idx[q * 196 + key];
                    u = f2u(rpb[idx * 32 + h] * LOG2E);
                }
                e.s[r] = u;
            }
            unsigned int off = (((h * 13 + qt) * 7 + (nt >> 1)) * 64 + lane) * 8
                               + (nt & 1) * 4;
            *(uint2*)(biasM + off) = e.v;
        }
        return;
    }
    if (blockIdx.x >= 392) return;

    const int r0 = blockIdx.x * 64;     // token rows (both branches stacked)
    const int j0 = blockIdx.y * 64;     // cols of 384

    for (int idx = tid; idx < 2048; idx += 256) {
        int row = idx >> 5, k0 = (idx & 31) << 2;
        int r = r0 + row;
        const float* xp = (r >= 12544) ? x2 : x1;
        int rem = r - ((r >= 12544) ? 12544 : 0);
        float4 v = *(const float4*)&xp[rem * 128 + k0];
        ushort4 u; u.x = f2u(v.x); u.y = f2u(v.y); u.z = f2u(v.z); u.w = f2u(v.w);
        *(ushort4*)&AT[row][k0] = u;
    }
    for (int idx = tid; idx < 2048; idx += 256) {
        int row = idx >> 5, k0 = (idx & 31) << 2;
        float4 v = *(const float4*)&qkvw[(j0 + row) * 128 + k0];
        ushort4 u; u.x = f2u(v.x); u.y = f2u(v.y); u.z = f2u(v.z); u.w = f2u(v.w);
        *(ushort4*)&BT[row][k0] = u;
    }
    __syncthreads();

    const int lane = tid & 63, w = tid >> 6;
    const int wj = (w >> 1) * 32;    // j offset (M dim)
    const int wt = (w & 1) * 32;     // token offset (N dim)
    const int quad = lane >> 4, tc = lane & 15;

    f32x4 acc[2][2] = {};
#pragma unroll
    for (int ks = 0; ks < 4; ++ks) {
        int k0 = ks * 32 + quad * 8;
        bf16x8 a0 = *(const bf16x8*)&BT[wj + tc][k0];
        bf16x8 a1 = *(const bf16x8*)&BT[wj + 16 + tc][k0];
        bf16x8 b0 = *(const bf16x8*)&AT[wt + tc][k0];
        bf16x8 b1 = *(const bf16x8*)&AT[wt + 16 + tc][k0];
        acc[0][0] = __builtin_amdgcn_mfma_f32_16x16x32_bf16(a0, b0, acc[0][0], 0, 0, 0);
        acc[0][1] = __builtin_amdgcn_mfma_f32_16x16x32_bf16(a0, b1, acc[0][1], 0, 0, 0);
        acc[1][0] = __builtin_amdgcn_mfma_f32_16x16x32_bf16(a1, b0, acc[1][0], 0, 0, 0);
        acc[1][1] = __builtin_amdgcn_mfma_f32_16x16x32_bf16(a1, b1, acc[1][1], 0, 0, 0);
    }

    const int sel = j0 >> 7;   // 0=q 1=k 2=v, uniform per block
#pragma unroll
    for (int mi = 0; mi < 2; ++mi) {
        int jbase = (j0 + wj + mi * 16 + quad * 4) & 127;
        int hh = jbase >> 2;
#pragma unroll
        for (int ni = 0; ni < 2; ++ni) {
            int tok = r0 + wt + ni * 16 + tc;
            int branch = (tok >= 12544) ? 1 : 0;
            int rem = tok - branch * 12544;
            int bb = rem / 196;
            int nn = rem - bb * 196;
            union { uint2 v; unsigned short s[4]; } pk2;
            if (sel == 0) {
#pragma unroll
                for (int r = 0; r < 4; ++r) pk2.s[r] = f2u(acc[mi][ni][r] * QSCALE);
                *(uint2*)&Qb[((bb * 32 + hh) * 196 + nn) * 8 + branch * 4] = pk2.v;
            } else if (sel == 1) {
#pragma unroll
                for (int r = 0; r < 4; ++r) pk2.s[r] = f2u(acc[mi][ni][r]);
                *(uint2*)&Kb[((bb * 32 + hh) * 196 + nn) * 8 + branch * 4] = pk2.v;
            } else {
#pragma unroll
                for (int r = 0; r < 4; ++r) pk2.s[r] = f2u(acc[mi][ni][r]);
                *(uint2*)&V[(bb * 64 + branch * 32 + hh) * 784 + nn * 4] = pk2.v;
            }
        }
    }
}

// ---------------------------------------------------------------------------
// Kernel 2: conv-gated value fusion + InstanceNorm + sigmoid(relu).
// Grid (64 b, 8 o-quads). Thread t<196 owns nd=4t..4t+3 (784 = 4*196 exact).
// uint2 loads (4 bf16) per channel -> 64 loads/thread (was ~200 scalar).
// ---------------------------------------------------------------------------
__device__ __forceinline__ float block_sum(float v, float* red, int tid) {
#pragma unroll
    for (int off = 32; off > 0; off >>= 1) v += __shfl_down(v, off);
    __syncthreads();
    if ((tid & 63) == 0) red[tid >> 6] = v;
    __syncthreads();
    return red[0] + red[1] + red[2] + red[3];
}

__device__ __forceinline__ float act_sig_relu(float x) {
    return x > 0.f ? __fdividef(1.f, 1.f + __expf(-x)) : 0.5f;
}

extern "C" __global__ __launch_bounds__(256) void fuse_kernel(
    const unsigned short* __restrict__ V,
    const float* __restrict__ fuse_w,
    const float* __restrict__ fuse_b,
    float* __restrict__ Vf)
{
    const int b = blockIdx.x, o0 = blockIdx.y * 4;
    const int tid = threadIdx.x;
    __shared__ float fws[4][64];
    __shared__ float red[4];
    fws[tid >> 6][tid & 63] = fuse_w[(o0 + (tid >> 6)) * 64 + (tid & 63)];
    __syncthreads();

    const bool act = tid < 196;
    const unsigned short* Vb = V + b * 64 * 784 + tid * 4;
    float4 a[4] = {};
    for (int c = 0; c < 64; ++c) {
        float4 x = {0.f, 0.f, 0.f, 0.f};
        if (act) {
            uint2 u = *(const uint2*)(Vb + c * 784);
            union { unsigned int i; float f; } z;
            z.i = u.x << 16;          x.x = z.f;
            z.i = u.x & 0xffff0000u;  x.y = z.f;
            z.i = u.y << 16;          x.z = z.f;
            z.i = u.y & 0xffff0000u;  x.w = z.f;
        }
#pragma unroll
        for (int o = 0; o < 4; ++o) {
            float w0 = fws[o][c];
            a[o].x = fmaf(w0, x.x, a[o].x);
            a[o].y = fmaf(w0, x.y, a[o].y);
            a[o].z = fmaf(w0, x.z, a[o].z);
            a[o].w = fmaf(w0, x.w, a[o].w);
        }
    }

    const float inv784 = 1.0f / 784.0f;
#pragma unroll
    for (int o = 0; o < 4; ++o) {
        float fb0 = fuse_b[o0 + o];
        float4 v = a[o];
        if (act) { v.x += fb0; v.y += fb0; v.z += fb0; v.w += fb0; }
        float s = v.x + v.y + v.z + v.w;
        float q = v.x*v.x + v.y*v.y + v.z*v.z + v.w*v.w;
        float S = block_sum(s, red, tid);
        float Q = block_sum(q, red, tid);
        float mu = S * inv784;
        float rstd = rsqrtf(Q * inv784 - mu * mu + 1e-5f);
        if (act) {
            float4 o4;
            o4.x = act_sig_relu((v.x - mu) * rstd);
            o4.y = act_sig_relu((v.y - mu) * rstd);
            o4.z = act_sig_relu((v.z - mu) * rstd);
            o4.w = act_sig_relu((v.w - mu) * rstd);
            *(float4*)&Vf[(b * 32 + o0 + o) * 784 + tid * 4] = o4;
        }
    }
}

// ---------------------------------------------------------------------------
// Kernel 3: MFMA attention, permute-free. S^T = K·Q^T (bias as C-init, one
// uint4/tile, prefetched per qt). exp2 in-register, v_perm pack; 16x16x16
// B-frag == C-frag layout -> PV direct. Dual O accumulators (independent
// 7-deep chains). O^T = V'^T·P^T with ones-row rowsum; V'^T A-frags hoisted.
// ---------------------------------------------------------------------------
extern "C" __global__ __launch_bounds__(256) void attn_kernel(
    const unsigned short* __restrict__ Qb, const unsigned short* __restrict__ Kb,
    const float* __restrict__ Vf, const unsigned short* __restrict__ biasM,
    unsigned short* __restrict__ Ob)
{
    const int bh = blockIdx.x;
    const int b = bh >> 5, h = bh & 31;
    __shared__ alignas(16) unsigned short Qs[208][8];
    __shared__ alignas(16) unsigned short Ks[224][8];
    __shared__ alignas(16) unsigned short VT[16][232];
    const int tid = threadIdx.x;

    const unsigned short* Qrow = Qb + bh * 196 * 8;
    const unsigned short* Krow = Kb + bh * 196 * 8;
    if (tid < 208) {
        uint4 z = {0, 0, 0, 0};
        uint4 v = (tid < 196) ? *(const uint4*)(Qrow + tid * 8) : z;
        *(uint4*)&Qs[tid][0] = v;
    }
    if (tid < 224) {
        uint4 z = {0, 0, 0, 0};
        uint4 v = (tid < 196) ? *(const uint4*)(Krow + tid * 8) : z;
        *(uint4*)&Ks[tid][0] = v;
    }
    {
        unsigned int* vtw = (unsigned int*)&VT[0][0];
        for (int i = tid; i < (16 * 232) / 2; i += 256) vtw[i] = 0u;
    }
    __syncthreads();
    if (tid < 196) {
        float4 vv = *(const float4*)(Vf + bh * 784 + tid * 4);
        VT[0][tid] = f2u(vv.x); VT[1][tid] = f2u(vv.y);
        VT[2][tid] = f2u(vv.z); VT[3][tid] = f2u(vv.w);
        VT[4][tid] = 0x3F80;   // 1.0 bf16
    }
    __syncthreads();

    const int lane = tid & 63, wv = tid >> 6;
    const int quad = lane >> 4, tc = lane & 15;

    // Hoist V'^T 16x16x16 A-frags (qt-invariant): A[m=tc][k=quad*4+j], tile t
    bf16x4s vfr16[14];
#pragma unroll
    for (int t = 0; t < 14; ++t)
        vfr16[t] = *(const bf16x4s*)&VT[tc][t * 16 + quad * 4];

    const unsigned short* bias_h = biasM + (unsigned)(h * 13) * 3584;

    for (int qt = wv; qt < 13; qt += 4) {
        bf16x8 bq = {};
        if (quad == 0) bq = *(const bf16x8*)&Qs[qt * 16 + tc][0];
        const unsigned short* bias_q = bias_h + qt * 3584;
        uint4 bw[7];
#pragma unroll
        for (int kt = 0; kt < 7; ++kt)
            bw[kt] = *(const uint4*)(bias_q + kt * 512 + lane * 8);
        f32x4 O0 = {}, O1 = {};
#pragma unroll
        for (int kt = 0; kt < 7; ++kt) {
            f32x4 s0, s1;
            {
                union { unsigned int u; float f; } c;
                c.u = bw[kt].x << 16;          s0[0] = c.f;
                c.u = bw[kt].x & 0xffff0000u;  s0[1] = c.f;
                c.u = bw[kt].y << 16;          s0[2] = c.f;
                c.u = bw[kt].y & 0xffff0000u;  s0[3] = c.f;
                c.u = bw[kt].z << 16;          s1[0] = c.f;
                c.u = bw[kt].z & 0xffff0000u;  s1[1] = c.f;
                c.u = bw[kt].w << 16;          s1[2] = c.f;
                c.u = bw[kt].w & 0xffff0000u;  s1[3] = c.f;
            }
            bf16x8 ka0 = *(const bf16x8*)&Ks[(kt * 2 + 0) * 16 + tc][0];
            bf16x8 ka1 = *(const bf16x8*)&Ks[(kt * 2 + 1) * 16 + tc][0];
            s0 = __builtin_amdgcn_mfma_f32_16x16x32_bf16(ka0, bq, s0, 0, 0, 0);
            s1 = __builtin_amdgcn_mfma_f32_16x16x32_bf16(ka1, bq, s1, 0, 0, 0);
            float e0 = __builtin_amdgcn_exp2f(s0[0]);
            float e1 = __builtin_amdgcn_exp2f(s0[1]);
            float e2 = __builtin_amdgcn_exp2f(s0[2]);
            float e3 = __builtin_amdgcn_exp2f(s0[3]);
            float g0 = __builtin_amdgcn_exp2f(s1[0]);
            float g1 = __builtin_amdgcn_exp2f(s1[1]);
            float g2 = __builtin_amdgcn_exp2f(s1[2]);
            float g3 = __builtin_amdgcn_exp2f(s1[3]);
            union { int d[2]; bf16x4s v; } pf0, pf1;
            pf0.d[0] = (int)__builtin_amdgcn_perm(__float_as_uint(e1), __float_as_uint(e0), 0x07060302u);
            pf0.d[1] = (int)__builtin_amdgcn_perm(__float_as_uint(e3), __float_as_uint(e2), 0x07060302u);
            pf1.d[0] = (int)__builtin_amdgcn_perm(__float_as_uint(g1), __float_as_uint(g0), 0x07060302u);
            pf1.d[1] = (int)__builtin_amdgcn_perm(__float_as_uint(g3), __float_as_uint(g2), 0x07060302u);
            O0 = __builtin_amdgcn_mfma_f32_16x16x16bf16_1k(vfr16[kt * 2 + 0], pf0.v, O0, 0, 0, 0);
            O1 = __builtin_amdgcn_mfma_f32_16x16x16bf16_1k(vfr16[kt * 2 + 1], pf1.v, O1, 0, 0, 0);
        }
        f32x4 Oacc;
        Oacc[0] = O0[0] + O1[0];
        Oacc[1] = O0[1] + O1[1];
        Oacc[2] = O0[2] + O1[2];
        Oacc[3] = O0[3] + O1[3];
        // O^T C-frag: rows d=quad*4+reg, col=query=tc. Rowsum = row 4.
        float rs = __shfl(Oacc[0], 16 + tc);
        int q = qt * 16 + tc;
        if (quad == 0 && q < 196) {
            float inv = __builtin_amdgcn_rcpf(rs);
            union { uint2 v; unsigned short s[4]; } pk2;
            pk2.s[0] = f2u(Oacc[0] * inv);
            pk2.s[1] = f2u(Oacc[1] * inv);
            pk2.s[2] = f2u(Oacc[2] * inv);
            pk2.s[3] = f2u(Oacc[3] * inv);
            *(uint2*)&Ob[(b * 196 + q) * 128 + h * 4] = pk2.v;
        }
    }
}

// ---------------------------------------------------------------------------
// Kernel 4: output projection via MFMA bf16. out = Ob @ projW^T + b (fp32 out)
// ---------------------------------------------------------------------------
extern "C" __global__ __launch_bounds__(256) void proj_kernel(
    const unsigned short* __restrict__ Ob, const float* __restrict__ projw,
    const float* __restrict__ projb, float* __restrict__ out)
{
    __shared__ alignas(16) unsigned short AT[64][136];
    __shared__ alignas(16) unsigned short BT[64][136];
    const int tid = threadIdx.x;
    const int r0 = blockIdx.x * 64;
    const int j0 = blockIdx.y * 64;

    for (int idx = tid; idx < 1024; idx += 256) {
        int row = idx >> 4, k0 = (idx & 15) << 3;
        *(uint4*)&AT[row][k0] = *(const uint4*)&Ob[(r0 + row) * 128 + k0];
    }
    for (int idx = tid; idx < 2048; idx += 256) {
        int row = idx >> 5, k0 = (idx & 31) << 2;
        float4 v = *(const float4*)&projw[(j0 + row) * 128 + k0];
        ushort4 u; u.x = f2u(v.x); u.y = f2u(v.y); u.z = f2u(v.z); u.w = f2u(v.w);
        *(ushort4*)&BT[row][k0] = u;
    }
    __syncthreads();

    const int lane = tid & 63, w = tid >> 6;
    const int wm = (w >> 1) * 32, wn = (w & 1) * 32;
    const int quad = lane >> 4, tcol = lane & 15;

    f32x4 acc[2][2] = {};
#pragma unroll
    for (int ks = 0; ks < 4; ++ks) {
        int k0 = ks * 32 + quad * 8;
        bf16x8 a0 = *(const bf16x8*)&AT[wm + tcol][k0];
        bf16x8 a1 = *(const bf16x8*)&AT[wm + 16 + tcol][k0];
        bf16x8 b0 = *(const bf16x8*)&BT[wn + tcol][k0];
        bf16x8 b1 = *(const bf16x8*)&BT[wn + 16 + tcol][k0];
        acc[0][0] = __builtin_amdgcn_mfma_f32_16x16x32_bf16(a0, b0, acc[0][0], 0, 0, 0);
        acc[0][1] = __builtin_amdgcn_mfma_f32_16x16x32_bf16(a0, b1, acc[0][1], 0, 0, 0);
        acc[1][0] = __builtin_amdgcn_mfma_f32_16x16x32_bf16(a1, b0, acc[1][0], 0, 0, 0);
        acc[1][1] = __builtin_amdgcn_mfma_f32_16x16x32_bf16(a1, b1, acc[1][1], 0, 0, 0);
    }

#pragma unroll
    for (int mi = 0; mi < 2; ++mi) {
#pragma unroll
        for (int ni = 0; ni < 2; ++ni) {
            int j = j0 + wn + ni * 16 + tcol;
            float pb = projb[j];
#pragma unroll
            for (int reg = 0; reg < 4; ++reg) {
                int r = r0 + wm + mi * 16 + quad * 4 + reg;
                out[r * 128 + j] = acc[mi][ni][reg] + pb;
            }
        }
    }
}

// ---------------------------------------------------------------------------
extern "C" void kernel_launch(void* const* d_in, const int* in_sizes, int n_in,
                              void* d_out, int out_size, void* d_ws, size_t ws_size,
                              hipStream_t stream)
{
    const float* x1    = (const float*)d_in[0];
    const float* x2    = (const float*)d_in[1];
    const float* qkvw  = (const float*)d_in[2];
    const float* projw = (const float*)d_in[3];
    const float* projb = (const float*)d_in[4];
    const float* rpb   = (const float*)d_in[5];
    const float* fw    = (const float*)d_in[6];
    const float* fb    = (const float*)d_in[7];
    const int*   rel   = (const int*)d_in[8];
    float* out = (float*)d_out;

    char* w = (char*)d_ws;
    unsigned short* Qb  = (unsigned short*)(w);              //  6,422,528 B
    unsigned short* Kb  = (unsigned short*)(w + 6422528);    //  6,422,528 B
    unsigned short* V   = (unsigned short*)(w + 12845056);   //  6,422,528 B
    float*          Vf  = (float*)(w + 19267584);            //  6,422,528 B
    unsigned short* bM  = (unsigned short*)(w + 25690112);   //  2,981,888 B
    unsigned short* Ob  = (unsigned short*)(w + 28672000);   //  3,211,264 B

    qkv_bias  <<<dim3(416, 7), dim3(256), 0, stream>>>(x1, x2, qkvw, rel, rpb,
                                                       Qb, Kb, V, bM);
    fuse_kernel<<<dim3(64, 8),  dim3(256), 0, stream>>>(V, fw, fb, Vf);
    attn_kernel<<<dim3(2048),   dim3(256), 0, stream>>>(Qb, Kb, Vf, bM, Ob);
    proj_kernel<<<dim3(196, 2), dim3(256), 0, stream>>>(Ob, projw, projb, out);
}